// Round 5
// baseline (377.002 us; speedup 1.0000x reference)
//
#include <hip/hip_runtime.h>

// B=128, N=256, D=O=512. R = B*N = 32768 rows.
// Rows are independent through the whole 3-block MLP (only softmax crosses rows)
// => ONE mega-kernel does LN1+G1+tanh+LN2+G2+tanh+res+LN3+G3 per 64-row tile:
//   - A-plane (64x512 f16) persistent in LDS, XOR-swizzled, never leaves the CU
//   - W chunks (BK=32, 32 KB) double-buffered via global_load_lds
//   - h1 residual held in 32 VGPRs (packed f16x2)
//   - logits written f16 (LDS-assembled full lines)
// HBM: Obs 64 MB in + logits 32 MB out (vs ~450 MB in the 8-kernel pipeline).
// Then masked softmax over N (f16 logits in, fp32 out).

#define NN 256

typedef _Float16 f16;
typedef __attribute__((ext_vector_type(2))) _Float16 f16x2;
typedef __attribute__((ext_vector_type(4))) _Float16 f16x4;
typedef __attribute__((ext_vector_type(8))) _Float16 f16x8;
typedef __attribute__((ext_vector_type(4))) float f32x4;

__device__ __forceinline__ float fast_tanh(float x) {
  float e = __expf(2.f * x);
  return 1.f - 2.f * __builtin_amdgcn_rcpf(e + 1.f);
}
__device__ __forceinline__ void async_copy16(const void* g, void* l) {
  __builtin_amdgcn_global_load_lds(
      (const __attribute__((address_space(1))) unsigned int*)g,
      (__attribute__((address_space(3))) unsigned int*)l, 16, 0, 0);
}

// ---- Transpose + f16-cast weights: W[d][o] fp32 -> WT[o][d] f16 (3 stages) ----
__global__ void prep_w_kernel(const float* __restrict__ W1, const float* __restrict__ W2,
                              const float* __restrict__ W3, f16* __restrict__ WT) {
  int idx = blockIdx.x * 256 + threadIdx.x;
  int s   = idx >> 18;
  int rem = idx & 0x3FFFF;
  int o   = rem >> 9;
  int d   = rem & 511;
  const float* W = (s == 0) ? W1 : (s == 1) ? W2 : W3;
  WT[idx] = (f16)W[d * 512 + o];
}

// ---- Mega-kernel: whole MLP for a 64-row tile ----
__global__ __launch_bounds__(512, 2) void mega_kernel(
    const float* __restrict__ Obs, const f16* __restrict__ WT,
    const float* __restrict__ g1, const float* __restrict__ b1,
    const float* __restrict__ g2, const float* __restrict__ b2,
    const float* __restrict__ g3, const float* __restrict__ b3,
    f16* __restrict__ Lg) {
  __shared__ __align__(16) f16 sA[64 * 512];     // 64 KB persistent A-plane
  __shared__ __align__(16) f16 sW[2][512 * 32];  // 2x32 KB W chunk double-buffer
  __shared__ __align__(16) float2 sPart[512];
  __shared__ __align__(16) float2 sStat[64];

  const int t = threadIdx.x, lane = t & 63, wv = t >> 6;
  const int row16 = lane & 15, quad = lane >> 4;
  const int rBase = blockIdx.x * 64;

  // ---------- Phase 0: LN1(Obs) -> sA ----------
  {
    const float* src = Obs + (size_t)rBase * 512;
    float4 v[16];
    #pragma unroll
    for (int i = 0; i < 16; ++i)
      v[i] = *(const float4*)(src + i * 2048 + t * 4);
    #pragma unroll
    for (int i = 0; i < 16; ++i) {
      float s = v[i].x + v[i].y + v[i].z + v[i].w;
      float q = v[i].x * v[i].x + v[i].y * v[i].y + v[i].z * v[i].z + v[i].w * v[i].w;
      #pragma unroll
      for (int off = 1; off < 64; off <<= 1) {
        s += __shfl_xor(s, off, 64);
        q += __shfl_xor(q, off, 64);
      }
      if (lane == 0) sPart[i * 8 + wv] = make_float2(s, q);
    }
    __syncthreads();
    if (t < 64) {
      float2 p0 = sPart[(t >> 2) * 8 + (t & 3) * 2];
      float2 p1 = sPart[(t >> 2) * 8 + (t & 3) * 2 + 1];
      float s = p0.x + p1.x, q = p0.y + p1.y;
      float mean = s * (1.f / 512.f);
      float var  = q * (1.f / 512.f) - mean * mean;
      sStat[t] = make_float2(mean, 1.f / sqrtf(var + 1e-5f));
    }
    __syncthreads();
    const int colB = (t & 127) * 4;
    const float4 Gv = *(const float4*)(g1 + colB);
    const float4 Bv = *(const float4*)(b1 + colB);
    const int cb = colB >> 3;
    const int half = (t & 1) * 4;
    #pragma unroll
    for (int i = 0; i < 16; ++i) {
      int r = i * 4 + (t >> 7);
      float2 st = sStat[r];
      f16x4 o;
      o[0] = (f16)((v[i].x - st.x) * st.y * Gv.x + Bv.x);
      o[1] = (f16)((v[i].y - st.x) * st.y * Gv.y + Bv.y);
      o[2] = (f16)((v[i].z - st.x) * st.y * Gv.z + Bv.z);
      o[3] = (f16)((v[i].w - st.x) * st.y * Gv.w + Bv.w);
      *(f16x4*)&sA[r * 512 + ((cb ^ (r & 7)) << 3) + half] = o;
    }
  }
  __syncthreads();

  f32x4 acc[4][4];
  f16x2 h1p[4][4][2];

  const int lr = lane >> 2;                  // DMA: row within 16-row group
  const int gb = (lane & 3) ^ ((lane >> 3) & 3);  // global k-block for this lane
  const int bswz = (quad ^ ((row16 >> 1) & 3)) << 3;

  for (int stage = 0; stage < 3; ++stage) {
    const f16* Wg = WT + stage * 262144;
    #pragma unroll
    for (int m = 0; m < 4; ++m)
      #pragma unroll
      for (int n = 0; n < 4; ++n)
        acc[m][n] = (f32x4){0.f, 0.f, 0.f, 0.f};

    // prologue: chunk 0 -> buf 0
    #pragma unroll
    for (int p4 = 0; p4 < 4; ++p4) {
      int rb = wv * 64 + p4 * 16;
      async_copy16(Wg + (size_t)(rb + lr) * 512 + gb * 8, &sW[0][rb * 32]);
    }
    __syncthreads();

    for (int i = 0; i < 16; ++i) {
      if (i < 15) {                          // prefetch chunk i+1 into other buf
        int k0n = (i + 1) * 32;
        f16* buf = sW[(i + 1) & 1];
        #pragma unroll
        for (int p4 = 0; p4 < 4; ++p4) {
          int rb = wv * 64 + p4 * 16;
          async_copy16(Wg + (size_t)(rb + lr) * 512 + k0n + gb * 8, buf + rb * 32);
        }
      }
      const f16* bufc = sW[i & 1];
      int K0B = i * 4;
      f16x8 af[4], bf[4];
      #pragma unroll
      for (int m = 0; m < 4; ++m) {
        int ar = m * 16 + row16;
        af[m] = *(const f16x8*)&sA[ar * 512 + (((K0B + quad) ^ (ar & 7)) << 3)];
      }
      #pragma unroll
      for (int n = 0; n < 4; ++n) {
        int br = wv * 64 + n * 16 + row16;
        bf[n] = *(const f16x8*)&bufc[br * 32 + bswz];
      }
      #pragma unroll
      for (int m = 0; m < 4; ++m)
        #pragma unroll
        for (int n = 0; n < 4; ++n)
          acc[m][n] = __builtin_amdgcn_mfma_f32_16x16x32_f16(af[m], bf[n], acc[m][n], 0, 0, 0);
      __syncthreads();   // prefetch drained + all reads of bufc done
    }

    if (stage < 2) {
      const float* Gp = (stage == 0) ? g2 : g3;
      const float* Bp = (stage == 0) ? b2 : b3;
      float gv[4], bv[4];
      #pragma unroll
      for (int n = 0; n < 4; ++n) {
        int c = wv * 64 + n * 16 + row16;
        gv[n] = Gp[c]; bv[n] = Bp[c];
      }
      #pragma unroll
      for (int m = 0; m < 4; ++m)
        #pragma unroll
        for (int n = 0; n < 4; ++n)
          #pragma unroll
          for (int rg = 0; rg < 4; ++rg) {
            float x = fast_tanh(acc[m][n][rg]);
            if (stage == 0) h1p[m][n][rg >> 1][rg & 1] = (f16)x;
            else            x += (float)h1p[m][n][rg >> 1][rg & 1];
            acc[m][n][rg] = x;
          }
      // per-row stats: partial over n, butterfly over row16
      #pragma unroll
      for (int m = 0; m < 4; ++m)
        #pragma unroll
        for (int rg = 0; rg < 4; ++rg) {
          float s = acc[m][0][rg] + acc[m][1][rg] + acc[m][2][rg] + acc[m][3][rg];
          float q = acc[m][0][rg] * acc[m][0][rg] + acc[m][1][rg] * acc[m][1][rg]
                  + acc[m][2][rg] * acc[m][2][rg] + acc[m][3][rg] * acc[m][3][rg];
          #pragma unroll
          for (int off = 1; off < 16; off <<= 1) {
            s += __shfl_xor(s, off, 16);
            q += __shfl_xor(q, off, 16);
          }
          if (row16 == 0) sPart[wv * 64 + m * 16 + quad * 4 + rg] = make_float2(s, q);
        }
      __syncthreads();
      if (t < 64) {
        float s = 0.f, q = 0.f;
        #pragma unroll
        for (int w = 0; w < 8; ++w) { float2 p = sPart[w * 64 + t]; s += p.x; q += p.y; }
        float mean = s * (1.f / 512.f);
        float var  = q * (1.f / 512.f) - mean * mean;
        sStat[t] = make_float2(mean, 1.f / sqrtf(var + 1e-5f));
      }
      __syncthreads();
      // write next A-plane = LN(x) into sA (swizzled)
      #pragma unroll
      for (int m = 0; m < 4; ++m)
        #pragma unroll
        for (int rg = 0; rg < 4; ++rg) {
          int r = m * 16 + quad * 4 + rg;
          float2 st = sStat[r];
          #pragma unroll
          for (int n = 0; n < 4; ++n) {
            int c = wv * 64 + n * 16 + row16;
            int p = (c >> 3) ^ (r & 7);
            sA[r * 512 + (p << 3) + (c & 7)] = (f16)((acc[m][n][rg] - st.x) * st.y * gv[n] + bv[n]);
          }
        }
      __syncthreads();
    } else {
      // logits -> LDS assemble (reuse sW, stride 520) in two 32-row halves -> f16 global
      f16* sE = (f16*)sW;
      #pragma unroll
      for (int half = 0; half < 2; ++half) {
        #pragma unroll
        for (int mh = 0; mh < 2; ++mh) {
          int m = half * 2 + mh;
          #pragma unroll
          for (int n = 0; n < 4; ++n) {
            int c = wv * 64 + n * 16 + row16;
            #pragma unroll
            for (int rg = 0; rg < 4; ++rg)
              sE[(mh * 16 + quad * 4 + rg) * 520 + c] = (f16)acc[m][n][rg];
          }
        }
        __syncthreads();
        #pragma unroll
        for (int j = 0; j < 4; ++j) {
          int gi = t + j * 512;
          int r = gi >> 6, cg = (gi & 63) * 8;
          f16x8 o = *(const f16x8*)&sE[r * 520 + cg];
          *(f16x8*)&Lg[((size_t)(rBase + half * 32 + r)) * 512 + cg] = o;
        }
        __syncthreads();
      }
    }
  }
}

// ---- Masked softmax over N: one block per (b, 64-o chunk), f16 logits in ----
__global__ __launch_bounds__(256, 2) void softmax_kernel(const f16* __restrict__ o3,
                                                         const int* __restrict__ mask,
                                                         float* __restrict__ out) {
  __shared__ float sz[NN * 64];
  __shared__ float sredm[4 * 64];
  __shared__ float sreds[4 * 64];
  __shared__ int   smask[NN];

  int b  = blockIdx.x >> 3;
  int oc = blockIdx.x & 7;
  int t  = threadIdx.x;
  int o_l = t & 63;
  int n_h = t >> 6;

  int mt = mask[b * NN + t];
  int any = __syncthreads_or(mt);
  smask[t] = (t == 0 && !any) ? 1 : mt;
  __syncthreads();

  const f16* src = o3 + (((size_t)(b * NN)) << 9) + oc * 64;
  #pragma unroll 4
  for (int j = 0; j < 64; ++j) {
    int n = j * 4 + n_h;
    float v = (float)src[((size_t)n << 9) + o_l];
    sz[n * 64 + o_l] = smask[n] ? v : -3.4e38f;
  }
  __syncthreads();

  float mx = -3.4e38f;
  #pragma unroll 8
  for (int i = 0; i < 64; ++i)
    mx = fmaxf(mx, sz[(n_h * 64 + i) * 64 + o_l]);
  sredm[n_h * 64 + o_l] = mx;
  __syncthreads();
  float m4 = fmaxf(fmaxf(sredm[o_l], sredm[64 + o_l]),
                   fmaxf(sredm[128 + o_l], sredm[192 + o_l]));

  float sm = 0.f;
  #pragma unroll 8
  for (int i = 0; i < 64; ++i)
    sm += __expf(sz[(n_h * 64 + i) * 64 + o_l] - m4);
  sreds[n_h * 64 + o_l] = sm;
  __syncthreads();
  float tot = sreds[o_l] + sreds[64 + o_l] + sreds[128 + o_l] + sreds[192 + o_l];
  float inv = 1.f / tot;

  float* dst = out + (((size_t)(b * NN)) << 9) + oc * 64;
  #pragma unroll 4
  for (int j = 0; j < 64; ++j) {
    int n = j * 4 + n_h;
    dst[((size_t)n << 9) + o_l] = __expf(sz[n * 64 + o_l] - m4) * inv;
  }
}

extern "C" void kernel_launch(void* const* d_in, const int* in_sizes, int n_in,
                              void* d_out, int out_size, void* d_ws, size_t ws_size,
                              hipStream_t stream) {
  const float* Obs = (const float*)d_in[0];
  const int*   msk = (const int*)d_in[1];
  const float* g1  = (const float*)d_in[2];
  const float* b1  = (const float*)d_in[3];
  const float* W1  = (const float*)d_in[4];
  const float* g2  = (const float*)d_in[5];
  const float* b2  = (const float*)d_in[6];
  const float* W2  = (const float*)d_in[7];
  const float* g3  = (const float*)d_in[8];
  const float* b3  = (const float*)d_in[9];
  const float* W3  = (const float*)d_in[10];
  float* out = (float*)d_out;

  char* ws = (char*)d_ws;
  const size_t MB = 1u << 20;
  f16* Lg = (f16*)ws;              // 32 MB f16 logits
  f16* WT = (f16*)(ws + 32 * MB);  // 1.5 MB

  prep_w_kernel<<<3072, 256, 0, stream>>>(W1, W2, W3, WT);
  mega_kernel<<<512, 512, 0, stream>>>(Obs, WT, g1, b1, g2, b2, g3, b3, Lg);
  softmax_kernel<<<1024, 256, 0, stream>>>(Lg, msk, out);
}

// Round 6
// 356.246 us; speedup vs baseline: 1.0583x; 1.0583x over previous
//
#include <hip/hip_runtime.h>

// B=128, N=256, D=O=512. R = B*N = 32768 rows.
// ONE mega-kernel does LN1+G1+tanh+LN2+G2+tanh+res+LN3+G3 per 64-row tile:
//   - A-plane (64x512 f16) persistent in LDS, XOR-swizzled
//   - W chunks (BK=32) double-buffered via global_load_lds; sW rows are
//     WAVE-PRIVATE (wave w stages and reads rows [64w,64w+64)) => K-loop has
//     NO __syncthreads, only per-wave s_waitcnt vmcnt(4) (AITER-style).
//   - h1 residual in 32 VGPRs (f16x2)
//   - launch_bounds(512,1): VGPR cap 256 (R5's (512,2) capped at 128 -> 230 MB
//     of scratch spill traffic, the whole regression)
// Then masked softmax over N (f16 logits in, fp32 out).

#define NN 256

typedef _Float16 f16;
typedef __attribute__((ext_vector_type(2))) _Float16 f16x2;
typedef __attribute__((ext_vector_type(4))) _Float16 f16x4;
typedef __attribute__((ext_vector_type(8))) _Float16 f16x8;
typedef __attribute__((ext_vector_type(4))) float f32x4;

__device__ __forceinline__ float fast_tanh(float x) {
  float e = __expf(2.f * x);
  return 1.f - 2.f * __builtin_amdgcn_rcpf(e + 1.f);
}
__device__ __forceinline__ void async_copy16(const void* g, void* l) {
  __builtin_amdgcn_global_load_lds(
      (const __attribute__((address_space(1))) unsigned int*)g,
      (__attribute__((address_space(3))) unsigned int*)l, 16, 0, 0);
}

// ---- Transpose + f16-cast weights: W[d][o] fp32 -> WT[o][d] f16 (3 stages) ----
__global__ void prep_w_kernel(const float* __restrict__ W1, const float* __restrict__ W2,
                              const float* __restrict__ W3, f16* __restrict__ WT) {
  int idx = blockIdx.x * 256 + threadIdx.x;
  int s   = idx >> 18;
  int rem = idx & 0x3FFFF;
  int o   = rem >> 9;
  int d   = rem & 511;
  const float* W = (s == 0) ? W1 : (s == 1) ? W2 : W3;
  WT[idx] = (f16)W[d * 512 + o];
}

// ---- Mega-kernel: whole MLP for a 64-row tile ----
__global__ __launch_bounds__(512, 1) void mega_kernel(
    const float* __restrict__ Obs, const f16* __restrict__ WT,
    const float* __restrict__ g1, const float* __restrict__ b1,
    const float* __restrict__ g2, const float* __restrict__ b2,
    const float* __restrict__ g3, const float* __restrict__ b3,
    f16* __restrict__ Lg) {
  __shared__ __align__(16) f16 sA[64 * 512];     // 64 KB persistent A-plane
  __shared__ __align__(16) f16 sW[2][512 * 32];  // 2x32 KB W chunk double-buffer
  __shared__ __align__(16) float2 sPart[512];
  __shared__ __align__(16) float2 sStat[64];

  const int t = threadIdx.x, lane = t & 63, wv = t >> 6;
  const int row16 = lane & 15, quad = lane >> 4;
  const int rBase = blockIdx.x * 64;

  // ---------- Phase 0: LN1(Obs) -> sA ----------
  {
    const float* src = Obs + (size_t)rBase * 512;
    float4 v[16];
    #pragma unroll
    for (int i = 0; i < 16; ++i)
      v[i] = *(const float4*)(src + i * 2048 + t * 4);
    #pragma unroll
    for (int i = 0; i < 16; ++i) {
      float s = v[i].x + v[i].y + v[i].z + v[i].w;
      float q = v[i].x * v[i].x + v[i].y * v[i].y + v[i].z * v[i].z + v[i].w * v[i].w;
      #pragma unroll
      for (int off = 1; off < 64; off <<= 1) {
        s += __shfl_xor(s, off, 64);
        q += __shfl_xor(q, off, 64);
      }
      if (lane == 0) sPart[i * 8 + wv] = make_float2(s, q);
    }
    __syncthreads();
    if (t < 64) {
      float2 p0 = sPart[(t >> 2) * 8 + (t & 3) * 2];
      float2 p1 = sPart[(t >> 2) * 8 + (t & 3) * 2 + 1];
      float s = p0.x + p1.x, q = p0.y + p1.y;
      float mean = s * (1.f / 512.f);
      float var  = q * (1.f / 512.f) - mean * mean;
      sStat[t] = make_float2(mean, 1.f / sqrtf(var + 1e-5f));
    }
    __syncthreads();
    const int colB = (t & 127) * 4;
    const float4 Gv = *(const float4*)(g1 + colB);
    const float4 Bv = *(const float4*)(b1 + colB);
    const int cb = colB >> 3;
    const int half = (t & 1) * 4;
    #pragma unroll
    for (int i = 0; i < 16; ++i) {
      int r = i * 4 + (t >> 7);
      float2 st = sStat[r];
      f16x4 o;
      o[0] = (f16)((v[i].x - st.x) * st.y * Gv.x + Bv.x);
      o[1] = (f16)((v[i].y - st.x) * st.y * Gv.y + Bv.y);
      o[2] = (f16)((v[i].z - st.x) * st.y * Gv.z + Bv.z);
      o[3] = (f16)((v[i].w - st.x) * st.y * Gv.w + Bv.w);
      *(f16x4*)&sA[r * 512 + ((cb ^ (r & 7)) << 3) + half] = o;
    }
  }
  __syncthreads();

  f32x4 acc[4][4];
  f16x2 h1p[4][4][2];

  const int lr = lane >> 2;                       // DMA: row within 16-row group
  const int gb = (lane & 3) ^ ((lane >> 3) & 3);  // global k-block for this lane
  const int bswz = (quad ^ ((row16 >> 1) & 3)) << 3;

  for (int stage = 0; stage < 3; ++stage) {
    const f16* Wg = WT + stage * 262144;
    #pragma unroll
    for (int m = 0; m < 4; ++m)
      #pragma unroll
      for (int n = 0; n < 4; ++n)
        acc[m][n] = (f32x4){0.f, 0.f, 0.f, 0.f};

    // prologue: chunk 0 -> buf 0 (wave-private rows)
    #pragma unroll
    for (int p4 = 0; p4 < 4; ++p4) {
      int rb = wv * 64 + p4 * 16;
      async_copy16(Wg + (size_t)(rb + lr) * 512 + gb * 8, &sW[0][rb * 32]);
    }

    for (int i = 0; i < 16; ++i) {
      if (i < 15) {                          // prefetch chunk i+1 into other buf
        int k0n = (i + 1) * 32;
        f16* buf = sW[(i + 1) & 1];
        #pragma unroll
        for (int p4 = 0; p4 < 4; ++p4) {
          int rb = wv * 64 + p4 * 16;
          async_copy16(Wg + (size_t)(rb + lr) * 512 + k0n + gb * 8, buf + rb * 32);
        }
        __builtin_amdgcn_s_waitcnt(0x0F74);  // vmcnt(4): chunk i landed, i+1 in flight
      } else {
        __builtin_amdgcn_s_waitcnt(0x0F70);  // vmcnt(0)
      }
      const f16* bufc = sW[i & 1];
      int K0B = i * 4;
      f16x8 af[4], bf[4];
      #pragma unroll
      for (int m = 0; m < 4; ++m) {
        int ar = m * 16 + row16;
        af[m] = *(const f16x8*)&sA[ar * 512 + (((K0B + quad) ^ (ar & 7)) << 3)];
      }
      #pragma unroll
      for (int n = 0; n < 4; ++n) {
        int br = wv * 64 + n * 16 + row16;
        bf[n] = *(const f16x8*)&bufc[br * 32 + bswz];
      }
      #pragma unroll
      for (int m = 0; m < 4; ++m)
        #pragma unroll
        for (int n = 0; n < 4; ++n)
          acc[m][n] = __builtin_amdgcn_mfma_f32_16x16x32_f16(af[m], bf[n], acc[m][n], 0, 0, 0);
    }

    if (stage < 2) {
      const float* Gp = (stage == 0) ? g2 : g3;
      const float* Bp = (stage == 0) ? b2 : b3;
      float gv[4], bv[4];
      #pragma unroll
      for (int n = 0; n < 4; ++n) {
        int c = wv * 64 + n * 16 + row16;
        gv[n] = Gp[c]; bv[n] = Bp[c];
      }
      #pragma unroll
      for (int m = 0; m < 4; ++m)
        #pragma unroll
        for (int n = 0; n < 4; ++n)
          #pragma unroll
          for (int rg = 0; rg < 4; ++rg) {
            float x = fast_tanh(acc[m][n][rg]);
            if (stage == 0) h1p[m][n][rg >> 1][rg & 1] = (f16)x;
            else            x += (float)h1p[m][n][rg >> 1][rg & 1];
            acc[m][n][rg] = x;
          }
      // per-row stats: partial over n, butterfly over row16
      #pragma unroll
      for (int m = 0; m < 4; ++m)
        #pragma unroll
        for (int rg = 0; rg < 4; ++rg) {
          float s = acc[m][0][rg] + acc[m][1][rg] + acc[m][2][rg] + acc[m][3][rg];
          float q = acc[m][0][rg] * acc[m][0][rg] + acc[m][1][rg] * acc[m][1][rg]
                  + acc[m][2][rg] * acc[m][2][rg] + acc[m][3][rg] * acc[m][3][rg];
          #pragma unroll
          for (int off = 1; off < 16; off <<= 1) {
            s += __shfl_xor(s, off, 16);
            q += __shfl_xor(q, off, 16);
          }
          if (row16 == 0) sPart[wv * 64 + m * 16 + quad * 4 + rg] = make_float2(s, q);
        }
      __syncthreads();   // all waves past K-loop (sA reads done) + sPart ready
      if (t < 64) {
        float s = 0.f, q = 0.f;
        #pragma unroll
        for (int w = 0; w < 8; ++w) { float2 p = sPart[w * 64 + t]; s += p.x; q += p.y; }
        float mean = s * (1.f / 512.f);
        float var  = q * (1.f / 512.f) - mean * mean;
        sStat[t] = make_float2(mean, 1.f / sqrtf(var + 1e-5f));
      }
      __syncthreads();
      // write next A-plane = LN(x) into sA (swizzled)
      #pragma unroll
      for (int m = 0; m < 4; ++m)
        #pragma unroll
        for (int rg = 0; rg < 4; ++rg) {
          int r = m * 16 + quad * 4 + rg;
          float2 st = sStat[r];
          #pragma unroll
          for (int n = 0; n < 4; ++n) {
            int c = wv * 64 + n * 16 + row16;
            int p = (c >> 3) ^ (r & 7);
            sA[r * 512 + (p << 3) + (c & 7)] = (f16)((acc[m][n][rg] - st.x) * st.y * gv[n] + bv[n]);
          }
        }
      __syncthreads();
    } else {
      // logits -> LDS assemble (reuse sW, stride 520) in two 32-row halves -> f16 global
      __syncthreads();   // ALL waves done with sW before sE overlays it
      f16* sE = (f16*)sW;
      #pragma unroll
      for (int half = 0; half < 2; ++half) {
        #pragma unroll
        for (int mh = 0; mh < 2; ++mh) {
          int m = half * 2 + mh;
          #pragma unroll
          for (int n = 0; n < 4; ++n) {
            int c = wv * 64 + n * 16 + row16;
            #pragma unroll
            for (int rg = 0; rg < 4; ++rg)
              sE[(mh * 16 + quad * 4 + rg) * 520 + c] = (f16)acc[m][n][rg];
          }
        }
        __syncthreads();
        #pragma unroll
        for (int j = 0; j < 4; ++j) {
          int gi = t + j * 512;
          int r = gi >> 6, cg = (gi & 63) * 8;
          f16x8 o = *(const f16x8*)&sE[r * 520 + cg];
          *(f16x8*)&Lg[((size_t)(rBase + half * 32 + r)) * 512 + cg] = o;
        }
        __syncthreads();
      }
    }
  }
}

// ---- Masked softmax over N: one block per (b, 64-o chunk), f16 logits in ----
__global__ __launch_bounds__(256, 2) void softmax_kernel(const f16* __restrict__ o3,
                                                         const int* __restrict__ mask,
                                                         float* __restrict__ out) {
  __shared__ float sz[NN * 64];
  __shared__ float sredm[4 * 64];
  __shared__ float sreds[4 * 64];
  __shared__ int   smask[NN];

  int b  = blockIdx.x >> 3;
  int oc = blockIdx.x & 7;
  int t  = threadIdx.x;
  int o_l = t & 63;
  int n_h = t >> 6;

  int mt = mask[b * NN + t];
  int any = __syncthreads_or(mt);
  smask[t] = (t == 0 && !any) ? 1 : mt;
  __syncthreads();

  const f16* src = o3 + (((size_t)(b * NN)) << 9) + oc * 64;
  #pragma unroll 4
  for (int j = 0; j < 64; ++j) {
    int n = j * 4 + n_h;
    float v = (float)src[((size_t)n << 9) + o_l];
    sz[n * 64 + o_l] = smask[n] ? v : -3.4e38f;
  }
  __syncthreads();

  float mx = -3.4e38f;
  #pragma unroll 8
  for (int i = 0; i < 64; ++i)
    mx = fmaxf(mx, sz[(n_h * 64 + i) * 64 + o_l]);
  sredm[n_h * 64 + o_l] = mx;
  __syncthreads();
  float m4 = fmaxf(fmaxf(sredm[o_l], sredm[64 + o_l]),
                   fmaxf(sredm[128 + o_l], sredm[192 + o_l]));

  float sm = 0.f;
  #pragma unroll 8
  for (int i = 0; i < 64; ++i)
    sm += __expf(sz[(n_h * 64 + i) * 64 + o_l] - m4);
  sreds[n_h * 64 + o_l] = sm;
  __syncthreads();
  float tot = sreds[o_l] + sreds[64 + o_l] + sreds[128 + o_l] + sreds[192 + o_l];
  float inv = 1.f / tot;

  float* dst = out + (((size_t)(b * NN)) << 9) + oc * 64;
  #pragma unroll 4
  for (int j = 0; j < 64; ++j) {
    int n = j * 4 + n_h;
    dst[((size_t)n << 9) + o_l] = __expf(sz[n * 64 + o_l] - m4) * inv;
  }
}

extern "C" void kernel_launch(void* const* d_in, const int* in_sizes, int n_in,
                              void* d_out, int out_size, void* d_ws, size_t ws_size,
                              hipStream_t stream) {
  const float* Obs = (const float*)d_in[0];
  const int*   msk = (const int*)d_in[1];
  const float* g1  = (const float*)d_in[2];
  const float* b1  = (const float*)d_in[3];
  const float* W1  = (const float*)d_in[4];
  const float* g2  = (const float*)d_in[5];
  const float* b2  = (const float*)d_in[6];
  const float* W2  = (const float*)d_in[7];
  const float* g3  = (const float*)d_in[8];
  const float* b3  = (const float*)d_in[9];
  const float* W3  = (const float*)d_in[10];
  float* out = (float*)d_out;

  char* ws = (char*)d_ws;
  const size_t MB = 1u << 20;
  f16* Lg = (f16*)ws;              // 32 MB f16 logits
  f16* WT = (f16*)(ws + 32 * MB);  // 1.5 MB

  prep_w_kernel<<<3072, 256, 0, stream>>>(W1, W2, W3, WT);
  mega_kernel<<<512, 512, 0, stream>>>(Obs, WT, g1, b1, g2, b2, g3, b3, Lg);
  softmax_kernel<<<1024, 256, 0, stream>>>(Lg, msk, out);
}